// Round 13
// baseline (267.141 us; speedup 1.0000x reference)
//
#include <hip/hip_runtime.h>

#define NB 16
#define NT 960000
#define NS 6001
#define TOPK 15
#define NSTEPS 6000
#define CHUNK 150
#define NCHUNK 40
#define FLOORV -100000.0f

typedef __attribute__((ext_vector_type(8))) short short8;
typedef __attribute__((ext_vector_type(4))) float f32x4;
typedef __attribute__((ext_vector_type(2))) float f32x2;
typedef __attribute__((ext_vector_type(4))) unsigned int u32x4;

// ---- workspace layout (offsets in floats) ----
constexpr size_t OFF_NACW  = 0;                                    // 216 floats (INVERSE nacw)
constexpr size_t OFF_WIN   = 256;                                  // 257 floats (hann window)
constexpr size_t OFF_FREQ  = 576;
constexpr size_t PERFR     = (size_t)NB * NS * 16;                 // per-frame arrays, K padded to 16
constexpr size_t OFF_LFV   = OFF_FREQ + PERFR;                     // packed: voiced? +log2(f) : -log2(f)
constexpr size_t OFF_DELTA = OFF_LFV + PERFR;
constexpr size_t OFF_GPK   = OFF_DELTA + PERFR;                    // gpeak partials NB*64
constexpr size_t OFF_P     = OFF_GPK + PERFR;                      // NB*NCHUNK*256 chunk matrices
constexpr size_t OFF_VENT  = OFF_P + (size_t)NB * NCHUNK * 256;    // NB*(NCHUNK+1)*16 entry vectors
constexpr size_t OFF_VFIN  = OFF_VENT + (size_t)NB * (NCHUNK + 1) * 16; // unused
constexpr size_t OFF_F0    = OFF_VFIN + 256;                       // NB*NS f0 (pre-median)
constexpr size_t OFF_BS    = OFF_F0 + 96032;                       // (unused)
constexpr size_t OFF_PTR   = OFF_BS + 2048;                        // uint8 ptrs NB*NSTEPS*16 bytes
constexpr size_t OFF_BMAP  = OFF_PTR + (size_t)NB * NSTEPS * 4;    // uint8 backmaps NB*NCHUNK*16 bytes

__device__ __forceinline__ unsigned ordf(float f) {
  unsigned u = __float_as_uint(f);
  return (u & 0x80000000u) ? ~u : (u | 0x80000000u);
}

// transition cost from packed lf-values (sign bit = unvoiced)
__device__ __forceinline__ float tr_of(float sa, float sb) {
  int xs = __float_as_int(sa) ^ __float_as_int(sb);
  float t = 0.35f * fabsf(sa - sb);
  t = (__float_as_int(sa) < 0) ? 0.f : t;   // both unvoiced -> 0
  return (xs < 0) ? 0.14f : t;              // mixed -> C_VUV
}

// ---------- K0: gpeak partials (per-block slot, no atomic) + setup in block(0,0) ----------
__global__ __launch_bounds__(256) void k_init(const float* __restrict__ x, float* __restrict__ ws) {
  const int b = blockIdx.y;
  const float4* xb = (const float4*)(x + (size_t)b * NT);
  const int n4 = NT / 4;
  float m = 0.f;
  for (int i = blockIdx.x * blockDim.x + threadIdx.x; i < n4; i += gridDim.x * blockDim.x) {
    float4 v = xb[i];
    m = fmaxf(m, fmaxf(fmaxf(fabsf(v.x), fabsf(v.y)), fmaxf(fabsf(v.z), fabsf(v.w))));
  }
  for (int off = 32; off; off >>= 1) m = fmaxf(m, __shfl_down(m, off));
  __shared__ float sm[4];
  if ((threadIdx.x & 63) == 0) sm[threadIdx.x >> 6] = m;
  __syncthreads();
  if (threadIdx.x == 0) {
    m = fmaxf(fmaxf(sm[0], sm[1]), fmaxf(sm[2], sm[3]));
    ws[OFF_GPK + b * 64 + blockIdx.x] = m;   // plain store to own slot
  }
  if (blockIdx.x == 0 && b == 0) {
    __shared__ float win[257];
    __shared__ float w0sh;
    const int tid = threadIdx.x;
    for (int n = tid; n < 257; n += 256) {
      float w = 0.5f * (1.0f - cosf((6.2831855f * (float)n) / 257.0f));
      win[n] = w;
      ws[OFF_WIN + n] = w;
    }
    __syncthreads();
    float s = 0.f;
    if (tid < 216) {
      for (int n = 0; n + tid < 257; ++n) s += win[n] * win[n + tid];
    }
    if (tid == 0) w0sh = s;
    __syncthreads();
    if (tid < 216) ws[OFF_NACW + tid] = w0sh / s;   // inverse of nacw
  }
}

__device__ __forceinline__ unsigned bf16rne(float f) {
  unsigned u = __float_as_uint(f);
  return (u + 0x7FFFu + ((u >> 16) & 1u)) >> 16;   // bf16 bits in low 16
}

__device__ __forceinline__ short8 bfrag(const char* p, int sh) {
  unsigned w0 = *(const unsigned*)(p);
  unsigned w1 = *(const unsigned*)(p + 4);
  unsigned w2 = *(const unsigned*)(p + 8);
  unsigned w3 = *(const unsigned*)(p + 12);
  unsigned w4 = *(const unsigned*)(p + 16);
  u32x4 o;
  o[0] = __builtin_amdgcn_alignbit(w1, w0, sh);
  o[1] = __builtin_amdgcn_alignbit(w2, w1, sh);
  o[2] = __builtin_amdgcn_alignbit(w3, w2, sh);
  o[3] = __builtin_amdgcn_alignbit(w4, w3, sh);
  return __builtin_bit_cast(short8, o);
}

// ---------- K1: one wave = one frame; bf16x3-split MFMA ACF; parallel top-k ----------
// per-wave LDS (floats), REGION-REUSED for 8 blocks/CU occupancy:
//   phase 1 (staging+MFMA): HI bf16[576] @[0,288) | LO @[288,576)
//   phase 2 (scatter):      ACF @[576,800)
//   phase 3 (candidates):   TQ @[0,216) over HI | LG @[288,504) over LO
//   phase 4 (top-k):        CK u64 @[800,1224) | SEL @[1224,1240)
__global__ __launch_bounds__(256, 8) void k_frames(const float* __restrict__ x, float* __restrict__ ws) {
  const int wv = threadIdx.x >> 6;
  const int g  = threadIdx.x & 63;
  const int s  = blockIdx.x * 4 + wv;
  const int b  = blockIdx.y;
  __shared__ __align__(16) float LA[4][1240];
  if (s >= NS) return;
  float* L = LA[wv];
  char* Lb = (char*)L;
  const size_t xb = (size_t)b * NT;
  const int c0 = 40 * s;               // float4 chunk base

  // ---- load frame ----
  float4 xv = make_float4(0.f, 0.f, 0.f, 0.f);
  if (c0 + g < NT / 4) xv = ((const float4*)(x + xb))[c0 + g];
  float x256 = 0.f;
  if (g == 0) {
    int i256 = 160 * s + 256;
    if (i256 < NT) x256 = x[xb + i256];
  }

  // ---- batch gpeak from partials (fmax of the same 64 block maxima: bit-identical) ----
  float gp = ws[OFF_GPK + b * 64 + g];
#pragma unroll
  for (int off = 32; off; off >>= 1) gp = fmaxf(gp, __shfl_xor(gp, off));

  // ---- mean over 257 raw samples ----
  float ps = ((xv.x + xv.y) + (xv.z + xv.w)) + x256;
#pragma unroll
  for (int off = 32; off; off >>= 1) ps += __shfl_xor(ps, off);
  const float mean = ps / 257.0f;

  // ---- window + local peak ----
  float4 w4 = ((const float4*)(ws + OFF_WIN))[g];
  float4 f4;
  f4.x = (xv.x - mean) * w4.x;
  f4.y = (xv.y - mean) * w4.y;
  f4.z = (xv.z - mean) * w4.z;
  f4.w = (xv.w - mean) * w4.w;
  float fr256 = 0.f;
  if (g == 0) fr256 = (x256 - mean) * ws[OFF_WIN + 256];
  float apk = fmaxf(fmaxf(fabsf(f4.x), fabsf(f4.y)), fmaxf(fabsf(f4.z), fabsf(f4.w)));
  if (g == 0) apk = fmaxf(apk, fabsf(fr256));
#pragma unroll
  for (int off = 32; off; off >>= 1) apk = fmaxf(apk, __shfl_xor(apk, off));

  // ---- build hi/lo bf16 buffers: buf[i] = fr[i-16], zero-padded to 576 elems ----
  {
    unsigned hx = bf16rne(f4.x), hy = bf16rne(f4.y), hz = bf16rne(f4.z), hw = bf16rne(f4.w);
    float lx = f4.x - __uint_as_float(hx << 16);
    float ly = f4.y - __uint_as_float(hy << 16);
    float lz = f4.z - __uint_as_float(hz << 16);
    float lw = f4.w - __uint_as_float(hw << 16);
    unsigned ph0 = hx | (hy << 16), ph1 = hz | (hw << 16);
    unsigned pl0 = bf16rne(lx) | (bf16rne(ly) << 16);
    unsigned pl1 = bf16rne(lz) | (bf16rne(lw) << 16);
    if (g < 8) { L[g] = 0.f; L[288 + g] = 0.f; }                     // elems 0..15
    f32x2 vh = {__uint_as_float(ph0), __uint_as_float(ph1)};
    f32x2 vl = {__uint_as_float(pl0), __uint_as_float(pl1)};
    *(f32x2*)&L[8 + 2 * g] = vh;                                     // elems 16+4g..19+4g
    *(f32x2*)&L[288 + 8 + 2 * g] = vl;
    {                                                                // elems 272..527 zero (A reads <=527 w/ kk<=8)
      f32x2 z = {0.f, 0.f};
      *(f32x2*)&L[136 + 2 * g] = z;
      *(f32x2*)&L[288 + 136 + 2 * g] = z;
    }
    if (g == 0) {                                                    // patch elem 272 = fr[256]
      unsigned h2 = bf16rne(fr256);
      float l2 = fr256 - __uint_as_float(h2 << 16);
      ((unsigned short*)Lb)[272] = (unsigned short)h2;
      ((unsigned short*)(Lb + 1152))[272] = (unsigned short)bf16rne(l2);
    }
  }
  __builtin_amdgcn_wave_barrier();

  // ---- ACF via MFMA: C[a][b] = sum_k buf[k+16a]*buf[k+b] = acf[16a-b] ----
  // kk=9 dropped: for k>=288, buf[k+16a] = 0 for all a (last nonzero elem = 272),
  // so that iteration contributes exactly +0.0 — bit-identical acf.
  const int bcol = g & 15, h = g >> 4;
  const int sh = 16 * (bcol & 1);
  const int hi4 = ((bcol & 3) >= 2) ? 4 : 0;
  const int Ab0 = 16 * h + 32 * bcol;
  const int Bb0 = 16 * h + ((2 * bcol) & ~7) + hi4;
  const char* Hb = Lb;
  const char* Ob = Lb + 1152;
  f32x4 acc = {0.f, 0.f, 0.f, 0.f};
#pragma unroll
  for (int kk = 0; kk < 9; ++kk) {
    short8 ah = __builtin_bit_cast(short8, *(const u32x4*)(Hb + Ab0 + 64 * kk));
    short8 al = __builtin_bit_cast(short8, *(const u32x4*)(Ob + Ab0 + 64 * kk));
    short8 bh = bfrag(Hb + Bb0 + 64 * kk, sh);
    short8 bl = bfrag(Ob + Bb0 + 64 * kk, sh);
    acc = __builtin_amdgcn_mfma_f32_16x16x32_bf16(ah, bh, acc, 0, 0, 0);
    acc = __builtin_amdgcn_mfma_f32_16x16x32_bf16(ah, bl, acc, 0, 0, 0);
    acc = __builtin_amdgcn_mfma_f32_16x16x32_bf16(al, bh, acc, 0, 0, 0);
  }
  __builtin_amdgcn_wave_barrier();
  // scatter: lane holds C rows 4h+r, col bcol
#pragma unroll
  for (int r = 0; r < 4; ++r) {
    int arow = 4 * h + r;
    int tau = 16 * arow - bcol;
    if (arow == 0 ? (bcol == 0) : (tau <= 215)) L[576 + (arow ? tau : 0)] = acc[r];
  }
  __builtin_amdgcn_wave_barrier();

  // ---- nacf + candidates (lane g<53: candidates 4g..4g+3); fq deferred ----
  const float inv0 = 1.0f / L[576];
  bool  flv[4] = {false, false, false, false};
  float lgv[4];
  if (g < 53) {
    f32x4 A4 = *(const f32x4*)&L[576 + 4 * g];
    f32x2 A2 = *(const f32x2*)&L[580 + 4 * g];
    f32x4 I4 = *(const f32x4*)(ws + OFF_NACW + 4 * g);
    f32x2 I2 = *(const f32x2*)(ws + OFF_NACW + 4 * g + 4);
    float nn[6];
    nn[0] = A4[0] * inv0 * I4[0];
    nn[1] = A4[1] * inv0 * I4[1];
    nn[2] = A4[2] * inv0 * I4[2];
    nn[3] = A4[3] * inv0 * I4[3];
    nn[4] = A2.x * inv0 * I2.x;
    nn[5] = A2.y * inv0 * I2.y;
    float tqv[4];
#pragma unroll
    for (int a = 0; a < 4; ++a) {
      float pm = nn[a], cm = nn[a + 1], nm = nn[a + 2];
      bool flag = (cm - pm >= 0.f) && (nm - cm <= 0.f) && (cm > 0.225f);
      float dr = (0.5f * (nm - pm)) / ((2.0f * cm - nm) - pm);   // exact div (decision-adjacent)
      float tq = dr + (float)(4 * g + a);
      tq = (tq > 0.f) ? tq : 0.f;     // NaN -> 0: output-invariant
      float l1p = __log2f(1.0f + tq);
      float lg = cm;
      if (lg > 1.0f) lg = __builtin_amdgcn_rcpf(lg);
      lg = lg - 0.01f * (l1p - 7.736965594166206f);   // == cm' - 0.01*log2(75/fq)
      flv[a] = flag;
      tqv[a] = tq;
      lgv[a] = flag ? lg : FLOORV;
    }
    f32x4 to_ = {tqv[0], tqv[1], tqv[2], tqv[3]};
    f32x4 lo_ = {lgv[0], lgv[1], lgv[2], lgv[3]};
    *(f32x4*)&L[0 + 4 * g] = to_;
    *(f32x4*)&L[288 + 4 * g] = lo_;
  }

  // ---- top-15 selection ----
  unsigned long long bb0b = __ballot(flv[0]);
  unsigned long long bb1 = __ballot(flv[1]);
  unsigned long long bb2 = __ballot(flv[2]);
  unsigned long long bb3 = __ballot(flv[3]);
  const int nv = __popcll(bb0b) + __popcll(bb1) + __popcll(bb2) + __popcll(bb3);
  int* sel = (int*)&L[1224];
  if (nv > 0) {
    unsigned long long below = (1ull << g) - 1ull;
    int base = __popcll(bb0b & below) + __popcll(bb1 & below) +
               __popcll(bb2 & below) + __popcll(bb3 & below);
    if (nv <= TOPK) {
      if (g < 53) {
        int cnt = base;
#pragma unroll
        for (int a = 0; a < 4; ++a) {
          int c = 4 * g + a;
          if (flv[a]) {
            sel[cnt] = c;
            ++cnt;
          } else {
            int ur = c - cnt;
            if (ur < TOPK - nv) sel[nv + ur] = c;
          }
        }
      }
    } else {
      unsigned long long* CK = (unsigned long long*)&L[800];   // 212 keys fit [800,1224)
      if (g < 53) {
        int cnt = base;
#pragma unroll
        for (int a = 0; a < 4; ++a) {
          if (flv[a]) {
            CK[cnt] = (((unsigned long long)ordf(lgv[a])) << 32)
                    | (unsigned long long)(0xFFFFFFFFu - (unsigned)(4 * g + a));
            ++cnt;
          }
        }
      }
      __builtin_amdgcn_wave_barrier();
      for (int l = g; l < nv; l += 64) {
        unsigned long long kl = CK[l];
        int rank = 0;
        for (int m = 0; m < nv; ++m) rank += (CK[m] > kl) ? 1 : 0;
        if (rank < TOPK) sel[rank] = (int)(0xFFFFFFFFu - (unsigned)(kl & 0xFFFFFFFFull));
      }
    }
  }
  __builtin_amdgcn_wave_barrier();

  // ---- per-frame outputs (lanes 0..15; slot 15 = fixed dead-state fill) ----
  if (g < 16) {
    size_t fi = ((size_t)b * NS + s) * 16 + g;
    if (g == TOPK) {
      ws[OFF_FREQ + fi] = 0.f;
      ws[OFF_LFV + fi] = -1.0f;   // unvoiced sentinel (state 15 is never selectable)
      ws[OFF_DELTA + fi] = 0.f;
    } else {
      int c = (nv == 0) ? g : sel[g];
      float tq = L[0 + c];
      float lg = L[288 + c];
      float fq = 16000.0f / (1.0f + tq);                  // same div, same input bits as before
      int voi = (lg > FLOORV) && (fq < 600.0f);
      float inten = (apk > gp) ? 1.0f : apk * __builtin_amdgcn_rcpf(gp);
      float luv = 0.45f + fmaxf(2.0f - inten * 48.333333333333336f, 0.f);
      float l2 = __log2f(fq);
      float dlt = voi ? (lg - 0.01f * (9.228818690495881f - l2)) : luv;
      ws[OFF_FREQ + fi] = fq;
      ws[OFF_LFV + fi] = voi ? l2 : -l2;
      ws[OFF_DELTA + fi] = dlt;
    }
  }
}

// ---------- K2: per-chunk max-plus product matrices (double-buffered, 1 barrier/step) ----------
__global__ __launch_bounds__(256) void k_chunkmat(float* __restrict__ ws) {
  const int c = blockIdx.x, b = blockIdx.y, tid = threadIdx.x;
  const int i = tid >> 4, j = tid & 15;
  __shared__ float MT[2][16][20];     // MT[buf][j][k], rows 80B (16B-aligned)
  __shared__ float Psh[2][16][20];
  const float* LFV = ws + OFF_LFV;
  const float* DEL = ws + OFF_DELTA;
  const size_t fb = (size_t)b * NS;
  const int t0 = c * CHUNK;
  float sA = LFV[(fb + t0) * 16 + i];
  float sB = LFV[(fb + t0 + 1) * 16 + j];
  float dB = DEL[(fb + t0 + 1) * 16 + j];
  Psh[0][i][j] = (i == j) ? 0.f : -INFINITY;   // max-plus identity
  int src = 0;
  float pn = 0.f;
  for (int s = 1; s <= CHUNK; ++s) {
    const int mb = s & 1;
    MT[mb][j][i] = dB - tr_of(sA, sB);         // transposed store
    __syncthreads();                            // MT[mb] + Psh[src] visible; prior reads done
    if (s < CHUNK) {
      const int t = t0 + s;
      sA = LFV[(fb + t) * 16 + i];
      sB = LFV[(fb + t + 1) * 16 + j];
      dB = DEL[(fb + t + 1) * 16 + j];
    }
    const float* Pr = &Psh[src][i][0];
    const float* Mr = &MT[mb][j][0];
    f32x4 t0v = *(const f32x4*)(Pr)      + *(const f32x4*)(Mr);
    f32x4 t1v = *(const f32x4*)(Pr + 4)  + *(const f32x4*)(Mr + 4);
    f32x4 t2v = *(const f32x4*)(Pr + 8)  + *(const f32x4*)(Mr + 8);
    f32x4 t3v = *(const f32x4*)(Pr + 12) + *(const f32x4*)(Mr + 12);
    f32x4 m01 = {fmaxf(t0v[0], t0v[1]), fmaxf(t0v[2], t0v[3]), fmaxf(t1v[0], t1v[1]), fmaxf(t1v[2], t1v[3])};
    f32x4 m23 = {fmaxf(t2v[0], t2v[1]), fmaxf(t2v[2], t2v[3]), fmaxf(t3v[0], t3v[1]), fmaxf(t3v[2], t3v[3])};
    pn = fmaxf(fmaxf(fmaxf(m01[0], m01[1]), fmaxf(m01[2], m01[3])),
               fmaxf(fmaxf(m23[0], m23[1]), fmaxf(m23[2], m23[3])));
    if (j == 15) pn = -INFINITY;               // dead column stays dead
    Psh[src ^ 1][i][j] = pn;
    src ^= 1;
  }
  ws[OFF_P + ((size_t)(b * NCHUNK + c)) * 256 + tid] = pn;
}

// ---------- K3: scan chunk matrices -> entry value vectors (1 wave / batch) ----------
__global__ __launch_bounds__(64) void k_scan(float* __restrict__ ws) {
  const int b = blockIdx.x, l = threadIdx.x;
  __shared__ float v[16];
  const float* DEL = ws + OFF_DELTA;
  const size_t fb = (size_t)b * NS;
  if (l < 16) {
    float d0 = DEL[fb * 16 + l];
    v[l] = d0;
    ws[OFF_VENT + ((size_t)b * (NCHUNK + 1)) * 16 + l] = d0;
  }
  __syncthreads();
  const float4* Pg = (const float4*)(ws + OFF_P + (size_t)b * NCHUNK * 256);
  const int k = l >> 2;
  float4 cur = Pg[l];    // element offset 4l = k*16 + (l&3)*4
  for (int c = 0; c < NCHUNK; ++c) {
    float4 nxt = cur;
    if (c + 1 < NCHUNK) nxt = Pg[(size_t)(c + 1) * 64 + l];
    float vk = (k < 15) ? v[k] : -INFINITY;
    float4 t;
    t.x = vk + cur.x; t.y = vk + cur.y; t.z = vk + cur.z; t.w = vk + cur.w;
    if (k == 15) { t.x = -INFINITY; t.y = -INFINITY; t.z = -INFINITY; t.w = -INFINITY; }
#pragma unroll
    for (int off = 4; off < 64; off <<= 1) {
      t.x = fmaxf(t.x, __shfl_xor(t.x, off));
      t.y = fmaxf(t.y, __shfl_xor(t.y, off));
      t.z = fmaxf(t.z, __shfl_xor(t.z, off));
      t.w = fmaxf(t.w, __shfl_xor(t.w, off));
    }
    __syncthreads();                 // all v[k] reads done before overwrite
    if (l < 4) {
      *(float4*)&v[4 * l] = *(float4*)&t;
      ((float4*)(ws + OFF_VENT + ((size_t)b * (NCHUNK + 1) + c + 1) * 16))[l] = *(float4*)&t;
    }
    __syncthreads();                 // new v visible
    cur = nxt;
  }
}

// ---------- K4: per-chunk sequential Viterbi (exact op order, 1 barrier/step) ----------
__global__ __launch_bounds__(256) void k_viterbi(float* __restrict__ ws) {
  const int c = blockIdx.x, b = blockIdx.y, tid = threadIdx.x;
  const int i = tid & 15, j = tid >> 4;
  __shared__ float val[2][16];
  __shared__ __align__(16) unsigned char ptl[CHUNK][16];
  const float* LFV = ws + OFF_LFV;
  const float* DEL = ws + OFF_DELTA;
  const size_t fb = (size_t)b * NS;
  const int t0 = c * CHUNK;
  if (tid < 16) {
    val[0][tid] = ws[OFF_VENT + ((size_t)b * (NCHUNK + 1) + c) * 16 + tid];
    val[1][tid] = -INFINITY;
  }
  float sA = LFV[(fb + t0) * 16 + i];
  float sB = LFV[(fb + t0 + 1) * 16 + j];
  float dB = DEL[(fb + t0 + 1) * 16 + j];
  int src = 0;
  for (int s = 1; s <= CHUNK; ++s) {
    __syncthreads();                 // val[src] writes from prev step visible; prev reads done
    float sc = (val[src][i] - tr_of(sA, sB)) + dB;   // reference op order
    if (i == 15) sc = -INFINITY;
    if (s < CHUNK) {
      const int t = t0 + s;
      sA = LFV[(fb + t) * 16 + i];
      sB = LFV[(fb + t + 1) * 16 + j];
      dB = DEL[(fb + t + 1) * 16 + j];
    }
    float mx = sc;
#pragma unroll
    for (int off = 1; off < 16; off <<= 1) mx = fmaxf(mx, __shfl_xor(mx, off));
    unsigned long long bal = __ballot(sc == mx);
    int nib = (int)((bal >> (tid & 48)) & 0xFFFFull);
    int bi = __ffs(nib) - 1;                     // lowest i on ties (reference argmax)
    if (i == 0 && j < 15) {
      val[src ^ 1][j] = mx;
      ptl[s - 1][j] = (unsigned char)bi;
    }
    src ^= 1;
  }
  __syncthreads();
  // dump ptrs coalesced (CHUNK*4 = 600 u32 > 256 threads -> loop)
  unsigned* pg = (unsigned*)(ws + OFF_PTR);
  for (int idx = tid; idx < CHUNK * 4; idx += 256)
    pg[((size_t)b * NSTEPS + t0) * 4 + idx] = ((unsigned*)ptl)[idx];
  // per-chunk backtrack map: exit state -> entry state
  if (tid < TOPK) {
    int st = tid;
#pragma unroll 1
    for (int s2 = CHUNK - 1; s2 >= 0; --s2) st = ptl[s2][st];
    ((unsigned char*)(ws + OFF_BMAP))[((size_t)(b * NCHUNK + c)) * 16 + tid] = (unsigned char)st;
  }
}

// ---------- K5: fused compose-replay + per-chunk state walk -> f0 ----------
__global__ __launch_bounds__(64) void k_sel(float* __restrict__ ws) {
  const int c = blockIdx.x, b = blockIdx.y, tid = threadIdx.x;
  const int t0 = c * CHUNK;
  __shared__ __align__(4) unsigned char pl[CHUNK][16];
  __shared__ __align__(4) unsigned char bmS[NCHUNK][16];
  __shared__ int bsS[NCHUNK + 1];
  __shared__ int stt[CHUNK + 1];
  const unsigned* pgu = (const unsigned*)((const unsigned char*)(ws + OFF_PTR) + ((size_t)b * NSTEPS + t0) * 16);
  for (int idx = tid; idx < CHUNK * 4; idx += 64) ((unsigned*)pl)[idx] = pgu[idx];
  const unsigned* bgu = (const unsigned*)((const unsigned char*)(ws + OFF_BMAP) + (size_t)b * NCHUNK * 16);
  for (int idx = tid; idx < NCHUNK * 4; idx += 64) ((unsigned*)bmS)[idx] = bgu[idx];
  __syncthreads();
  if (tid == 0) {
    float best = -INFINITY; int bi = 0;
    for (int jj = 0; jj < TOPK; ++jj) {
      float vv = ws[OFF_VENT + ((size_t)b * (NCHUNK + 1) + NCHUNK) * 16 + jj];
      if (vv > best) { best = vv; bi = jj; }   // strict > : first max
    }
    int st = bi;
    bsS[NCHUNK] = st;
    for (int cc = NCHUNK - 1; cc >= 0; --cc) { st = bmS[cc][st]; bsS[cc] = st; }
    int s2t = bsS[c + 1];
    stt[CHUNK] = s2t;
    for (int s2 = CHUNK; s2 >= 1; --s2) { s2t = pl[s2 - 1][s2t]; stt[s2 - 1] = s2t; }
  }
  __syncthreads();
  const int nt = (c == NCHUNK - 1) ? (CHUNK + 1) : CHUNK;
  for (int u = tid; u < nt; u += 64) {
    const int t = t0 + u;
    const int st = stt[u];
    size_t fi = ((size_t)b * NS + t) * 16 + st;
    float fq = ws[OFF_FREQ + fi];
    float lv = ws[OFF_LFV + fi];
    ws[OFF_F0 + (size_t)b * NS + t] = (lv > 0.f) ? fq : 0.f;
  }
}

// ---------- K6: median-5 with edge padding ----------
__global__ __launch_bounds__(256) void k_median(const float* __restrict__ ws, float* __restrict__ out) {
  const int b = blockIdx.y;
  const int t = blockIdx.x * 256 + threadIdx.x;
  if (t >= NS) return;
  const float* f0 = ws + OFF_F0 + (size_t)b * NS;
  float a0 = f0[max(t - 2, 0)];
  float a1 = f0[max(t - 1, 0)];
  float a2 = f0[t];
  float a3 = f0[min(t + 1, NS - 1)];
  float a4 = f0[min(t + 2, NS - 1)];
#define SW(u, w) { float lo_ = fminf(u, w), hi_ = fmaxf(u, w); u = lo_; w = hi_; }
  SW(a0, a1) SW(a1, a2) SW(a2, a3) SW(a3, a4)
  SW(a0, a1) SW(a1, a2) SW(a2, a3)
  SW(a0, a1) SW(a1, a2)
#undef SW
  out[(size_t)b * NS + t] = a2;
}

extern "C" void kernel_launch(void* const* d_in, const int* in_sizes, int n_in,
                              void* d_out, int out_size, void* d_ws, size_t ws_size,
                              hipStream_t stream) {
  const float* x = (const float*)d_in[0];
  float* ws = (float*)d_ws;
  float* out = (float*)d_out;
  hipLaunchKernelGGL(k_init, dim3(64, NB), dim3(256), 0, stream, x, ws);
  hipLaunchKernelGGL(k_frames, dim3((NS + 3) / 4, NB), dim3(256), 0, stream, x, ws);
  hipLaunchKernelGGL(k_chunkmat, dim3(NCHUNK, NB), dim3(256), 0, stream, ws);
  hipLaunchKernelGGL(k_scan, dim3(NB), dim3(64), 0, stream, ws);
  hipLaunchKernelGGL(k_viterbi, dim3(NCHUNK, NB), dim3(256), 0, stream, ws);
  hipLaunchKernelGGL(k_sel, dim3(NCHUNK, NB), dim3(64), 0, stream, ws);
  hipLaunchKernelGGL(k_median, dim3((NS + 255) / 256, NB), dim3(256), 0, stream, ws, out);
}

// Round 14
// 245.257 us; speedup vs baseline: 1.0892x; 1.0892x over previous
//
#include <hip/hip_runtime.h>

#define NB 16
#define NT 960000
#define NS 6001
#define TOPK 15
#define NSTEPS 6000
#define CHUNK 100
#define NCHUNK 60
#define FLOORV -100000.0f

typedef __attribute__((ext_vector_type(8))) short short8;
typedef __attribute__((ext_vector_type(4))) float f32x4;
typedef __attribute__((ext_vector_type(2))) float f32x2;
typedef __attribute__((ext_vector_type(4))) unsigned int u32x4;

// ---- workspace layout (offsets in floats) ----
constexpr size_t OFF_NACW  = 0;                                    // 216 floats (INVERSE nacw)
constexpr size_t OFF_WIN   = 256;                                  // 257 floats (hann window)
constexpr size_t OFF_FREQ  = 576;
constexpr size_t PERFR     = (size_t)NB * NS * 16;                 // per-frame arrays, K padded to 16
constexpr size_t OFF_LFV   = OFF_FREQ + PERFR;                     // packed: voiced? +log2(f) : -log2(f)
constexpr size_t OFF_DELTA = OFF_LFV + PERFR;
constexpr size_t OFF_GPK   = OFF_DELTA + PERFR;                    // gpeak partials NB*64
constexpr size_t OFF_P     = OFF_GPK + PERFR;                      // NB*NCHUNK*256 chunk matrices
constexpr size_t OFF_VENT  = OFF_P + (size_t)NB * NCHUNK * 256;    // NB*(NCHUNK+1)*16 entry vectors
constexpr size_t OFF_VFIN  = OFF_VENT + (size_t)NB * (NCHUNK + 1) * 16; // unused
constexpr size_t OFF_F0    = OFF_VFIN + 256;                       // NB*NS f0 (pre-median)
constexpr size_t OFF_BS    = OFF_F0 + 96032;                       // (unused)
constexpr size_t OFF_PTR   = OFF_BS + 2048;                        // uint8 ptrs NB*NSTEPS*16 bytes
constexpr size_t OFF_BMAP  = OFF_PTR + (size_t)NB * NSTEPS * 4;    // uint8 backmaps NB*NCHUNK*16 bytes

__device__ __forceinline__ unsigned ordf(float f) {
  unsigned u = __float_as_uint(f);
  return (u & 0x80000000u) ? ~u : (u | 0x80000000u);
}

// transition cost from packed lf-values (sign bit = unvoiced)
__device__ __forceinline__ float tr_of(float sa, float sb) {
  int xs = __float_as_int(sa) ^ __float_as_int(sb);
  float t = 0.35f * fabsf(sa - sb);
  t = (__float_as_int(sa) < 0) ? 0.f : t;   // both unvoiced -> 0
  return (xs < 0) ? 0.14f : t;              // mixed -> C_VUV
}

// ---------- K0: gpeak partials (per-block slot, no atomic) + setup in block(0,0) ----------
__global__ __launch_bounds__(256) void k_init(const float* __restrict__ x, float* __restrict__ ws) {
  const int b = blockIdx.y;
  const float4* xb = (const float4*)(x + (size_t)b * NT);
  const int n4 = NT / 4;
  float m = 0.f;
  for (int i = blockIdx.x * blockDim.x + threadIdx.x; i < n4; i += gridDim.x * blockDim.x) {
    float4 v = xb[i];
    m = fmaxf(m, fmaxf(fmaxf(fabsf(v.x), fabsf(v.y)), fmaxf(fabsf(v.z), fabsf(v.w))));
  }
  for (int off = 32; off; off >>= 1) m = fmaxf(m, __shfl_down(m, off));
  __shared__ float sm[4];
  if ((threadIdx.x & 63) == 0) sm[threadIdx.x >> 6] = m;
  __syncthreads();
  if (threadIdx.x == 0) {
    m = fmaxf(fmaxf(sm[0], sm[1]), fmaxf(sm[2], sm[3]));
    ws[OFF_GPK + b * 64 + blockIdx.x] = m;   // plain store to own slot
  }
  if (blockIdx.x == 0 && b == 0) {
    __shared__ float win[257];
    __shared__ float w0sh;
    const int tid = threadIdx.x;
    for (int n = tid; n < 257; n += 256) {
      float w = 0.5f * (1.0f - cosf((6.2831855f * (float)n) / 257.0f));
      win[n] = w;
      ws[OFF_WIN + n] = w;
    }
    __syncthreads();
    float s = 0.f;
    if (tid < 216) {
      for (int n = 0; n + tid < 257; ++n) s += win[n] * win[n + tid];
    }
    if (tid == 0) w0sh = s;
    __syncthreads();
    if (tid < 216) ws[OFF_NACW + tid] = w0sh / s;   // inverse of nacw
  }
}

__device__ __forceinline__ unsigned bf16rne(float f) {
  unsigned u = __float_as_uint(f);
  return (u + 0x7FFFu + ((u >> 16) & 1u)) >> 16;   // bf16 bits in low 16
}

__device__ __forceinline__ short8 bfrag(const char* p, int sh) {
  unsigned w0 = *(const unsigned*)(p);
  unsigned w1 = *(const unsigned*)(p + 4);
  unsigned w2 = *(const unsigned*)(p + 8);
  unsigned w3 = *(const unsigned*)(p + 12);
  unsigned w4 = *(const unsigned*)(p + 16);
  u32x4 o;
  o[0] = __builtin_amdgcn_alignbit(w1, w0, sh);
  o[1] = __builtin_amdgcn_alignbit(w2, w1, sh);
  o[2] = __builtin_amdgcn_alignbit(w3, w2, sh);
  o[3] = __builtin_amdgcn_alignbit(w4, w3, sh);
  return __builtin_bit_cast(short8, o);
}

// ---------- K1: one wave = one frame; bf16x3-split MFMA ACF; parallel top-k ----------
// per-wave LDS (floats), REGION-REUSED for 8 blocks/CU occupancy:
//   phase 1 (staging+MFMA): HI bf16[576] @[0,288) | LO @[288,576)
//   phase 2 (scatter):      ACF @[576,800)
//   phase 3 (candidates):   TQ @[0,216) over HI | LG @[288,504) over LO
//   phase 4 (top-k):        CK u64 @[800,1224) | SEL @[1224,1240)
__global__ __launch_bounds__(256, 8) void k_frames(const float* __restrict__ x, float* __restrict__ ws) {
  const int wv = threadIdx.x >> 6;
  const int g  = threadIdx.x & 63;
  const int s  = blockIdx.x * 4 + wv;
  const int b  = blockIdx.y;
  __shared__ __align__(16) float LA[4][1240];
  if (s >= NS) return;
  float* L = LA[wv];
  char* Lb = (char*)L;
  const size_t xb = (size_t)b * NT;
  const int c0 = 40 * s;               // float4 chunk base

  // ---- load frame ----
  float4 xv = make_float4(0.f, 0.f, 0.f, 0.f);
  if (c0 + g < NT / 4) xv = ((const float4*)(x + xb))[c0 + g];
  float x256 = 0.f;
  if (g == 0) {
    int i256 = 160 * s + 256;
    if (i256 < NT) x256 = x[xb + i256];
  }

  // ---- batch gpeak from partials (fmax of the same 64 block maxima: bit-identical) ----
  float gp = ws[OFF_GPK + b * 64 + g];
#pragma unroll
  for (int off = 32; off; off >>= 1) gp = fmaxf(gp, __shfl_xor(gp, off));

  // ---- mean over 257 raw samples ----
  float ps = ((xv.x + xv.y) + (xv.z + xv.w)) + x256;
#pragma unroll
  for (int off = 32; off; off >>= 1) ps += __shfl_xor(ps, off);
  const float mean = ps / 257.0f;

  // ---- window + local peak ----
  float4 w4 = ((const float4*)(ws + OFF_WIN))[g];
  float4 f4;
  f4.x = (xv.x - mean) * w4.x;
  f4.y = (xv.y - mean) * w4.y;
  f4.z = (xv.z - mean) * w4.z;
  f4.w = (xv.w - mean) * w4.w;
  float fr256 = 0.f;
  if (g == 0) fr256 = (x256 - mean) * ws[OFF_WIN + 256];
  float apk = fmaxf(fmaxf(fabsf(f4.x), fabsf(f4.y)), fmaxf(fabsf(f4.z), fabsf(f4.w)));
  if (g == 0) apk = fmaxf(apk, fabsf(fr256));
#pragma unroll
  for (int off = 32; off; off >>= 1) apk = fmaxf(apk, __shfl_xor(apk, off));

  // ---- build hi/lo bf16 buffers: buf[i] = fr[i-16] ----
  {
    unsigned hx = bf16rne(f4.x), hy = bf16rne(f4.y), hz = bf16rne(f4.z), hw = bf16rne(f4.w);
    float lx = f4.x - __uint_as_float(hx << 16);
    float ly = f4.y - __uint_as_float(hy << 16);
    float lz = f4.z - __uint_as_float(hz << 16);
    float lw = f4.w - __uint_as_float(hw << 16);
    unsigned ph0 = hx | (hy << 16), ph1 = hz | (hw << 16);
    unsigned pl0 = bf16rne(lx) | (bf16rne(ly) << 16);
    unsigned pl1 = bf16rne(lz) | (bf16rne(lw) << 16);
    if (g < 8) { L[g] = 0.f; L[288 + g] = 0.f; }                     // elems 0..15
    f32x2 vh = {__uint_as_float(ph0), __uint_as_float(ph1)};
    f32x2 vl = {__uint_as_float(pl0), __uint_as_float(pl1)};
    *(f32x2*)&L[8 + 2 * g] = vh;                                     // elems 16+4g..19+4g
    *(f32x2*)&L[288 + 8 + 2 * g] = vl;
    {                                                                // elems 272..527 zero (A reads cap at 527 w/ kk<=8)
      f32x2 z = {0.f, 0.f};
      *(f32x2*)&L[136 + 2 * g] = z;
      *(f32x2*)&L[288 + 136 + 2 * g] = z;
    }
    if (g == 0) {                                                    // patch elem 272 = fr[256]
      unsigned h2 = bf16rne(fr256);
      float l2 = fr256 - __uint_as_float(h2 << 16);
      ((unsigned short*)Lb)[272] = (unsigned short)h2;
      ((unsigned short*)(Lb + 1152))[272] = (unsigned short)bf16rne(l2);
    }
  }
  __builtin_amdgcn_wave_barrier();

  // ---- ACF via MFMA: C[a][b] = sum_k buf[k+16a]*buf[k+b] = acf[16a-b] ----
  // kk=9 dropped: for k>=288, buf[k+16a] = 0 for all a (last nonzero elem = 272),
  // so that iteration contributes exactly +0.0 — bit-identical acf.
  const int bcol = g & 15, h = g >> 4;
  const int sh = 16 * (bcol & 1);
  const int hi4 = ((bcol & 3) >= 2) ? 4 : 0;
  const int Ab0 = 16 * h + 32 * bcol;
  const int Bb0 = 16 * h + ((2 * bcol) & ~7) + hi4;
  const char* Hb = Lb;
  const char* Ob = Lb + 1152;
  f32x4 acc = {0.f, 0.f, 0.f, 0.f};
#pragma unroll
  for (int kk = 0; kk < 9; ++kk) {
    short8 ah = __builtin_bit_cast(short8, *(const u32x4*)(Hb + Ab0 + 64 * kk));
    short8 al = __builtin_bit_cast(short8, *(const u32x4*)(Ob + Ab0 + 64 * kk));
    short8 bh = bfrag(Hb + Bb0 + 64 * kk, sh);
    short8 bl = bfrag(Ob + Bb0 + 64 * kk, sh);
    acc = __builtin_amdgcn_mfma_f32_16x16x32_bf16(ah, bh, acc, 0, 0, 0);
    acc = __builtin_amdgcn_mfma_f32_16x16x32_bf16(ah, bl, acc, 0, 0, 0);
    acc = __builtin_amdgcn_mfma_f32_16x16x32_bf16(al, bh, acc, 0, 0, 0);
  }
  __builtin_amdgcn_wave_barrier();
  // scatter: lane holds C rows 4h+r, col bcol
#pragma unroll
  for (int r = 0; r < 4; ++r) {
    int arow = 4 * h + r;
    int tau = 16 * arow - bcol;
    if (arow == 0 ? (bcol == 0) : (tau <= 215)) L[576 + (arow ? tau : 0)] = acc[r];
  }
  __builtin_amdgcn_wave_barrier();

  // ---- nacf + candidates (lane g<53: candidates 4g..4g+3); fq deferred ----
  const float inv0 = 1.0f / L[576];
  bool  flv[4] = {false, false, false, false};
  float lgv[4];
  if (g < 53) {
    f32x4 A4 = *(const f32x4*)&L[576 + 4 * g];
    f32x2 A2 = *(const f32x2*)&L[580 + 4 * g];
    f32x4 I4 = *(const f32x4*)(ws + OFF_NACW + 4 * g);
    f32x2 I2 = *(const f32x2*)(ws + OFF_NACW + 4 * g + 4);
    float nn[6];
    nn[0] = A4[0] * inv0 * I4[0];
    nn[1] = A4[1] * inv0 * I4[1];
    nn[2] = A4[2] * inv0 * I4[2];
    nn[3] = A4[3] * inv0 * I4[3];
    nn[4] = A2.x * inv0 * I2.x;
    nn[5] = A2.y * inv0 * I2.y;
    float tqv[4];
#pragma unroll
    for (int a = 0; a < 4; ++a) {
      float pm = nn[a], cm = nn[a + 1], nm = nn[a + 2];
      bool flag = (cm - pm >= 0.f) && (nm - cm <= 0.f) && (cm > 0.225f);
      float dr = (0.5f * (nm - pm)) / ((2.0f * cm - nm) - pm);   // exact div (decision-adjacent)
      float tq = dr + (float)(4 * g + a);
      tq = (tq > 0.f) ? tq : 0.f;     // NaN -> 0: output-invariant
      float l1p = __log2f(1.0f + tq);
      float lg = cm;
      if (lg > 1.0f) lg = __builtin_amdgcn_rcpf(lg);
      lg = lg - 0.01f * (l1p - 7.736965594166206f);   // == cm' - 0.01*log2(75/fq)
      flv[a] = flag;
      tqv[a] = tq;
      lgv[a] = flag ? lg : FLOORV;
    }
    f32x4 to_ = {tqv[0], tqv[1], tqv[2], tqv[3]};
    f32x4 lo_ = {lgv[0], lgv[1], lgv[2], lgv[3]};
    *(f32x4*)&L[0 + 4 * g] = to_;
    *(f32x4*)&L[288 + 4 * g] = lo_;
  }

  // ---- top-15 selection ----
  unsigned long long bb0b = __ballot(flv[0]);
  unsigned long long bb1 = __ballot(flv[1]);
  unsigned long long bb2 = __ballot(flv[2]);
  unsigned long long bb3 = __ballot(flv[3]);
  const int nv = __popcll(bb0b) + __popcll(bb1) + __popcll(bb2) + __popcll(bb3);
  int* sel = (int*)&L[1224];
  if (nv > 0) {
    unsigned long long below = (1ull << g) - 1ull;
    int base = __popcll(bb0b & below) + __popcll(bb1 & below) +
               __popcll(bb2 & below) + __popcll(bb3 & below);
    if (nv <= TOPK) {
      if (g < 53) {
        int cnt = base;
#pragma unroll
        for (int a = 0; a < 4; ++a) {
          int c = 4 * g + a;
          if (flv[a]) {
            sel[cnt] = c;
            ++cnt;
          } else {
            int ur = c - cnt;
            if (ur < TOPK - nv) sel[nv + ur] = c;
          }
        }
      }
    } else {
      unsigned long long* CK = (unsigned long long*)&L[800];   // 212 keys fit [800,1224)
      if (g < 53) {
        int cnt = base;
#pragma unroll
        for (int a = 0; a < 4; ++a) {
          if (flv[a]) {
            CK[cnt] = (((unsigned long long)ordf(lgv[a])) << 32)
                    | (unsigned long long)(0xFFFFFFFFu - (unsigned)(4 * g + a));
            ++cnt;
          }
        }
      }
      __builtin_amdgcn_wave_barrier();
      for (int l = g; l < nv; l += 64) {
        unsigned long long kl = CK[l];
        int rank = 0;
        for (int m = 0; m < nv; ++m) rank += (CK[m] > kl) ? 1 : 0;
        if (rank < TOPK) sel[rank] = (int)(0xFFFFFFFFu - (unsigned)(kl & 0xFFFFFFFFull));
      }
    }
  }
  __builtin_amdgcn_wave_barrier();

  // ---- per-frame outputs (lanes 0..15; slot 15 = fixed dead-state fill) ----
  if (g < 16) {
    size_t fi = ((size_t)b * NS + s) * 16 + g;
    if (g == TOPK) {
      ws[OFF_FREQ + fi] = 0.f;
      ws[OFF_LFV + fi] = -1.0f;   // unvoiced sentinel (state 15 is never selectable)
      ws[OFF_DELTA + fi] = 0.f;
    } else {
      int c = (nv == 0) ? g : sel[g];
      float tq = L[0 + c];
      float lg = L[288 + c];
      float fq = 16000.0f / (1.0f + tq);                  // same div, same input bits as before
      int voi = (lg > FLOORV) && (fq < 600.0f);
      float inten = (apk > gp) ? 1.0f : apk * __builtin_amdgcn_rcpf(gp);
      float luv = 0.45f + fmaxf(2.0f - inten * 48.333333333333336f, 0.f);
      float l2 = __log2f(fq);
      float dlt = voi ? (lg - 0.01f * (9.228818690495881f - l2)) : luv;
      ws[OFF_FREQ + fi] = fq;
      ws[OFF_LFV + fi] = voi ? l2 : -l2;
      ws[OFF_DELTA + fi] = dlt;
    }
  }
}

// ---------- K2: per-chunk max-plus product matrices (double-buffered, 1 barrier/step) ----------
__global__ __launch_bounds__(256) void k_chunkmat(float* __restrict__ ws) {
  const int c = blockIdx.x, b = blockIdx.y, tid = threadIdx.x;
  const int i = tid >> 4, j = tid & 15;
  __shared__ float MT[2][16][20];     // MT[buf][j][k], rows 80B (16B-aligned)
  __shared__ float Psh[2][16][20];
  const float* LFV = ws + OFF_LFV;
  const float* DEL = ws + OFF_DELTA;
  const size_t fb = (size_t)b * NS;
  const int t0 = c * CHUNK;
  float sA = LFV[(fb + t0) * 16 + i];
  float sB = LFV[(fb + t0 + 1) * 16 + j];
  float dB = DEL[(fb + t0 + 1) * 16 + j];
  Psh[0][i][j] = (i == j) ? 0.f : -INFINITY;   // max-plus identity
  int src = 0;
  float pn = 0.f;
  for (int s = 1; s <= CHUNK; ++s) {
    const int mb = s & 1;
    MT[mb][j][i] = dB - tr_of(sA, sB);         // transposed store
    __syncthreads();                            // MT[mb] + Psh[src] visible; prior reads done
    if (s < CHUNK) {
      const int t = t0 + s;
      sA = LFV[(fb + t) * 16 + i];
      sB = LFV[(fb + t + 1) * 16 + j];
      dB = DEL[(fb + t + 1) * 16 + j];
    }
    const float* Pr = &Psh[src][i][0];
    const float* Mr = &MT[mb][j][0];
    f32x4 t0v = *(const f32x4*)(Pr)      + *(const f32x4*)(Mr);
    f32x4 t1v = *(const f32x4*)(Pr + 4)  + *(const f32x4*)(Mr + 4);
    f32x4 t2v = *(const f32x4*)(Pr + 8)  + *(const f32x4*)(Mr + 8);
    f32x4 t3v = *(const f32x4*)(Pr + 12) + *(const f32x4*)(Mr + 12);
    f32x4 m01 = {fmaxf(t0v[0], t0v[1]), fmaxf(t0v[2], t0v[3]), fmaxf(t1v[0], t1v[1]), fmaxf(t1v[2], t1v[3])};
    f32x4 m23 = {fmaxf(t2v[0], t2v[1]), fmaxf(t2v[2], t2v[3]), fmaxf(t3v[0], t3v[1]), fmaxf(t3v[2], t3v[3])};
    pn = fmaxf(fmaxf(fmaxf(m01[0], m01[1]), fmaxf(m01[2], m01[3])),
               fmaxf(fmaxf(m23[0], m23[1]), fmaxf(m23[2], m23[3])));
    if (j == 15) pn = -INFINITY;               // dead column stays dead
    Psh[src ^ 1][i][j] = pn;
    src ^= 1;
  }
  ws[OFF_P + ((size_t)(b * NCHUNK + c)) * 256 + tid] = pn;
}

// ---------- K3: scan chunk matrices -> entry value vectors (1 wave / batch) ----------
__global__ __launch_bounds__(64) void k_scan(float* __restrict__ ws) {
  const int b = blockIdx.x, l = threadIdx.x;
  __shared__ float v[16];
  const float* DEL = ws + OFF_DELTA;
  const size_t fb = (size_t)b * NS;
  if (l < 16) {
    float d0 = DEL[fb * 16 + l];
    v[l] = d0;
    ws[OFF_VENT + ((size_t)b * (NCHUNK + 1)) * 16 + l] = d0;
  }
  __syncthreads();
  const float4* Pg = (const float4*)(ws + OFF_P + (size_t)b * NCHUNK * 256);
  const int k = l >> 2;
  float4 cur = Pg[l];    // element offset 4l = k*16 + (l&3)*4
  for (int c = 0; c < NCHUNK; ++c) {
    float4 nxt = cur;
    if (c + 1 < NCHUNK) nxt = Pg[(size_t)(c + 1) * 64 + l];
    float vk = (k < 15) ? v[k] : -INFINITY;
    float4 t;
    t.x = vk + cur.x; t.y = vk + cur.y; t.z = vk + cur.z; t.w = vk + cur.w;
    if (k == 15) { t.x = -INFINITY; t.y = -INFINITY; t.z = -INFINITY; t.w = -INFINITY; }
#pragma unroll
    for (int off = 4; off < 64; off <<= 1) {
      t.x = fmaxf(t.x, __shfl_xor(t.x, off));
      t.y = fmaxf(t.y, __shfl_xor(t.y, off));
      t.z = fmaxf(t.z, __shfl_xor(t.z, off));
      t.w = fmaxf(t.w, __shfl_xor(t.w, off));
    }
    __syncthreads();                 // all v[k] reads done before overwrite
    if (l < 4) {
      *(float4*)&v[4 * l] = *(float4*)&t;
      ((float4*)(ws + OFF_VENT + ((size_t)b * (NCHUNK + 1) + c + 1) * 16))[l] = *(float4*)&t;
    }
    __syncthreads();                 // new v visible
    cur = nxt;
  }
}

// ---------- K4: per-chunk sequential Viterbi (exact op order, 1 barrier/step) ----------
__global__ __launch_bounds__(256) void k_viterbi(float* __restrict__ ws) {
  const int c = blockIdx.x, b = blockIdx.y, tid = threadIdx.x;
  const int i = tid & 15, j = tid >> 4;
  __shared__ float val[2][16];
  __shared__ __align__(16) unsigned char ptl[CHUNK][16];
  const float* LFV = ws + OFF_LFV;
  const float* DEL = ws + OFF_DELTA;
  const size_t fb = (size_t)b * NS;
  const int t0 = c * CHUNK;
  if (tid < 16) {
    val[0][tid] = ws[OFF_VENT + ((size_t)b * (NCHUNK + 1) + c) * 16 + tid];
    val[1][tid] = -INFINITY;
  }
  float sA = LFV[(fb + t0) * 16 + i];
  float sB = LFV[(fb + t0 + 1) * 16 + j];
  float dB = DEL[(fb + t0 + 1) * 16 + j];
  int src = 0;
  for (int s = 1; s <= CHUNK; ++s) {
    __syncthreads();                 // val[src] writes from prev step visible; prev reads done
    float sc = (val[src][i] - tr_of(sA, sB)) + dB;   // reference op order
    if (i == 15) sc = -INFINITY;
    if (s < CHUNK) {
      const int t = t0 + s;
      sA = LFV[(fb + t) * 16 + i];
      sB = LFV[(fb + t + 1) * 16 + j];
      dB = DEL[(fb + t + 1) * 16 + j];
    }
    float mx = sc;
#pragma unroll
    for (int off = 1; off < 16; off <<= 1) mx = fmaxf(mx, __shfl_xor(mx, off));
    unsigned long long bal = __ballot(sc == mx);
    int nib = (int)((bal >> (tid & 48)) & 0xFFFFull);
    int bi = __ffs(nib) - 1;                     // lowest i on ties (reference argmax)
    if (i == 0 && j < 15) {
      val[src ^ 1][j] = mx;
      ptl[s - 1][j] = (unsigned char)bi;
    }
    src ^= 1;
  }
  __syncthreads();
  // dump ptrs coalesced (CHUNK*4 = 400 u32 > 256 threads -> loop)
  unsigned* pg = (unsigned*)(ws + OFF_PTR);
  for (int idx = tid; idx < CHUNK * 4; idx += 256)
    pg[((size_t)b * NSTEPS + t0) * 4 + idx] = ((unsigned*)ptl)[idx];
  // per-chunk backtrack map: exit state -> entry state
  if (tid < TOPK) {
    int st = tid;
#pragma unroll 1
    for (int s2 = CHUNK - 1; s2 >= 0; --s2) st = ptl[s2][st];
    ((unsigned char*)(ws + OFF_BMAP))[((size_t)(b * NCHUNK + c)) * 16 + tid] = (unsigned char)st;
  }
}

// ---------- K5: fused compose-replay + per-chunk state walk -> f0 ----------
__global__ __launch_bounds__(64) void k_sel(float* __restrict__ ws) {
  const int c = blockIdx.x, b = blockIdx.y, tid = threadIdx.x;
  const int t0 = c * CHUNK;
  __shared__ __align__(4) unsigned char pl[CHUNK][16];
  __shared__ __align__(4) unsigned char bmS[NCHUNK][16];
  __shared__ int bsS[NCHUNK + 1];
  __shared__ int stt[CHUNK + 1];
  const unsigned* pgu = (const unsigned*)((const unsigned char*)(ws + OFF_PTR) + ((size_t)b * NSTEPS + t0) * 16);
  for (int idx = tid; idx < CHUNK * 4; idx += 64) ((unsigned*)pl)[idx] = pgu[idx];
  const unsigned* bgu = (const unsigned*)((const unsigned char*)(ws + OFF_BMAP) + (size_t)b * NCHUNK * 16);
  for (int idx = tid; idx < NCHUNK * 4; idx += 64) ((unsigned*)bmS)[idx] = bgu[idx];
  __syncthreads();
  if (tid == 0) {
    float best = -INFINITY; int bi = 0;
    for (int jj = 0; jj < TOPK; ++jj) {
      float vv = ws[OFF_VENT + ((size_t)b * (NCHUNK + 1) + NCHUNK) * 16 + jj];
      if (vv > best) { best = vv; bi = jj; }   // strict > : first max
    }
    int st = bi;
    bsS[NCHUNK] = st;
    for (int cc = NCHUNK - 1; cc >= 0; --cc) { st = bmS[cc][st]; bsS[cc] = st; }
    int s2t = bsS[c + 1];
    stt[CHUNK] = s2t;
    for (int s2 = CHUNK; s2 >= 1; --s2) { s2t = pl[s2 - 1][s2t]; stt[s2 - 1] = s2t; }
  }
  __syncthreads();
  const int nt = (c == NCHUNK - 1) ? (CHUNK + 1) : CHUNK;
  for (int u = tid; u < nt; u += 64) {
    const int t = t0 + u;
    const int st = stt[u];
    size_t fi = ((size_t)b * NS + t) * 16 + st;
    float fq = ws[OFF_FREQ + fi];
    float lv = ws[OFF_LFV + fi];
    ws[OFF_F0 + (size_t)b * NS + t] = (lv > 0.f) ? fq : 0.f;
  }
}

// ---------- K6: median-5 with edge padding ----------
__global__ __launch_bounds__(256) void k_median(const float* __restrict__ ws, float* __restrict__ out) {
  const int b = blockIdx.y;
  const int t = blockIdx.x * 256 + threadIdx.x;
  if (t >= NS) return;
  const float* f0 = ws + OFF_F0 + (size_t)b * NS;
  float a0 = f0[max(t - 2, 0)];
  float a1 = f0[max(t - 1, 0)];
  float a2 = f0[t];
  float a3 = f0[min(t + 1, NS - 1)];
  float a4 = f0[min(t + 2, NS - 1)];
#define SW(u, w) { float lo_ = fminf(u, w), hi_ = fmaxf(u, w); u = lo_; w = hi_; }
  SW(a0, a1) SW(a1, a2) SW(a2, a3) SW(a3, a4)
  SW(a0, a1) SW(a1, a2) SW(a2, a3)
  SW(a0, a1) SW(a1, a2)
#undef SW
  out[(size_t)b * NS + t] = a2;
}

extern "C" void kernel_launch(void* const* d_in, const int* in_sizes, int n_in,
                              void* d_out, int out_size, void* d_ws, size_t ws_size,
                              hipStream_t stream) {
  const float* x = (const float*)d_in[0];
  float* ws = (float*)d_ws;
  float* out = (float*)d_out;
  hipLaunchKernelGGL(k_init, dim3(64, NB), dim3(256), 0, stream, x, ws);
  hipLaunchKernelGGL(k_frames, dim3((NS + 3) / 4, NB), dim3(256), 0, stream, x, ws);
  hipLaunchKernelGGL(k_chunkmat, dim3(NCHUNK, NB), dim3(256), 0, stream, ws);
  hipLaunchKernelGGL(k_scan, dim3(NB), dim3(64), 0, stream, ws);
  hipLaunchKernelGGL(k_viterbi, dim3(NCHUNK, NB), dim3(256), 0, stream, ws);
  hipLaunchKernelGGL(k_sel, dim3(NCHUNK, NB), dim3(64), 0, stream, ws);
  hipLaunchKernelGGL(k_median, dim3((NS + 255) / 256, NB), dim3(256), 0, stream, ws, out);
}